// Round 1
// baseline (241.850 us; speedup 1.0000x reference)
//
#include <hip/hip_runtime.h>
#include <hip/hip_bf16.h>
#include <type_traits>

// out[b] = X[b] @ (X[b]^T @ X[b]);  B=8, S=4096, D=512, fp32 in/out.
// Strategy: bf16 MFMA for both GEMMs (fp32 accumulate).
//   k1: Xt = bf16 transpose of X, stashed in d_out (first 33.5MB of 67MB)
//   k2: gram(bf16, ws) = Xt · Xt^T   (M=N=512, K=4096) -- symmetric
//   k3: out(fp32)     = X · gram^T   (M=4096, N=512, K=512), A cast on the fly
// Stream ordering makes d_out reuse safe: k3 is the only writer after k2 reads Xt.

typedef __attribute__((ext_vector_type(8))) short short8;
typedef __attribute__((ext_vector_type(4))) float floatx4;

#define BM 128
#define BN 128
#define BK 32

#define BATCH 8
#define SEQ 4096
#define DIM 512

__device__ __forceinline__ void async_copy16(const __hip_bfloat16* g, __hip_bfloat16* l) {
  __builtin_amdgcn_global_load_lds((const __attribute__((address_space(1))) void*)g,
                                   (__attribute__((address_space(3))) void*)l, 16, 0, 0);
}

// ---------------- k1: transpose + cast -------------------------------------
__global__ __launch_bounds__(256) void transpose_cast_kernel(
    const float* __restrict__ X, __hip_bfloat16* __restrict__ Xt) {
  __shared__ float tile[64][65];
  const int b = blockIdx.z;
  const int s0 = blockIdx.x * 64;
  const int d0 = blockIdx.y * 64;
  const int tx = threadIdx.x & 63;
  const int ty = threadIdx.x >> 6;  // 0..3
  const float* Xb = X + (long)b * SEQ * DIM;
  __hip_bfloat16* Xtb = Xt + (long)b * DIM * SEQ;
#pragma unroll
  for (int r = 0; r < 64; r += 4)
    tile[r + ty][tx] = Xb[(long)(s0 + r + ty) * DIM + d0 + tx];
  __syncthreads();
#pragma unroll
  for (int r = 0; r < 64; r += 4)
    Xtb[(long)(d0 + r + ty) * SEQ + s0 + tx] = __float2bfloat16(tile[tx][r + ty]);
}

// ---------------- k2/k3: C = A · Bt^T (Bt stored [N][K], K-contiguous) ------
// AFP32=false: A is bf16 [M][K], staged via global_load_lds (width 16).
// AFP32=true : A is fp32 [M][K], staged via float4 loads + cast + ds_write.
template <bool AFP32, typename CT>
__global__ __launch_bounds__(256) void gemm_bt_kernel(
    const float* __restrict__ Af, const __hip_bfloat16* __restrict__ Ab,
    const __hip_bfloat16* __restrict__ Bt, CT* __restrict__ C,
    int K, int lda, int ldb, int ldc, long strideA, long strideB, long strideC) {
  __shared__ __align__(16) __hip_bfloat16 As[BM * BK];  // [m][k], 64B rows
  __shared__ __align__(16) __hip_bfloat16 Bs[BN * BK];  // [n][k]

  const int b = blockIdx.z;
  const int m0 = blockIdx.y * BM;
  const int n0 = blockIdx.x * BN;
  const int tid = threadIdx.x;
  const int w = tid >> 6;        // wave 0..3
  const int lane = tid & 63;
  const int r16 = lane & 15;     // MFMA row-sel / col-sel
  const int kg = lane >> 4;      // k-group 0..3
  const int wr = w >> 1;         // wave tile row (0..1) -> 64 rows
  const int wc = w & 1;          // wave tile col (0..1) -> 64 cols

  const float* Afb = AFP32 ? Af + b * strideA : nullptr;
  const __hip_bfloat16* Abb = AFP32 ? nullptr : Ab + b * strideA;
  const __hip_bfloat16* Btb = Bt + b * strideB;
  CT* Cb = C + b * strideC;

  const floatx4 vzero = {0.f, 0.f, 0.f, 0.f};
  floatx4 acc[4][4];
#pragma unroll
  for (int i = 0; i < 4; ++i)
#pragma unroll
    for (int j = 0; j < 4; ++j) acc[i][j] = vzero;

  for (int k0 = 0; k0 < K; k0 += BK) {
    // ---- stage B (always bf16, async direct-to-LDS) ----
#pragma unroll
    for (int q = 0; q < 2; ++q) {
      const __hip_bfloat16* gb =
          Btb + (long)(n0 + w * 32 + q * 16 + (lane >> 2)) * ldb + k0 + (lane & 3) * 8;
      async_copy16(gb, &Bs[(w * 32 + q * 16) * BK]);
    }
    // ---- stage A ----
    if constexpr (!AFP32) {
#pragma unroll
      for (int q = 0; q < 2; ++q) {
        const __hip_bfloat16* ga =
            Abb + (long)(m0 + w * 32 + q * 16 + (lane >> 2)) * lda + k0 + (lane & 3) * 8;
        async_copy16(ga, &As[(w * 32 + q * 16) * BK]);
      }
    } else {
      const int row = tid >> 1;           // 0..127
      const int half = tid & 1;           // 16-element half of the 32-wide row
      const float* ar = Afb + (long)(m0 + row) * lda + k0 + half * 16;
      float f[16];
      *(float4*)(f + 0)  = *(const float4*)(ar + 0);
      *(float4*)(f + 4)  = *(const float4*)(ar + 4);
      *(float4*)(f + 8)  = *(const float4*)(ar + 8);
      *(float4*)(f + 12) = *(const float4*)(ar + 12);
      union { short8 v[2]; __hip_bfloat16 e[16]; } u;
#pragma unroll
      for (int t = 0; t < 16; ++t) u.e[t] = __float2bfloat16(f[t]);
      short8* dst = (short8*)&As[row * BK + half * 16];
      dst[0] = u.v[0];
      dst[1] = u.v[1];
    }
    __syncthreads();  // compiler drains vmcnt for global_load_lds here

    short8 a[4], bfrag[4];
#pragma unroll
    for (int i = 0; i < 4; ++i)
      a[i] = *(const short8*)&As[(wr * 64 + i * 16 + r16) * BK + kg * 8];
#pragma unroll
    for (int j = 0; j < 4; ++j)
      bfrag[j] = *(const short8*)&Bs[(wc * 64 + j * 16 + r16) * BK + kg * 8];
#pragma unroll
    for (int i = 0; i < 4; ++i)
#pragma unroll
      for (int j = 0; j < 4; ++j)
        acc[i][j] = __builtin_amdgcn_mfma_f32_16x16x32_bf16(a[i], bfrag[j], acc[i][j], 0, 0, 0);
    __syncthreads();  // protect LDS from next iteration's staging
  }

  // ---- epilogue: C[m][n], row = kg*4 + reg, col = r16 (m89-verified map) ----
#pragma unroll
  for (int i = 0; i < 4; ++i) {
    const int row_base = m0 + wr * 64 + i * 16 + kg * 4;
#pragma unroll
    for (int j = 0; j < 4; ++j) {
      const int col = n0 + wc * 64 + j * 16 + r16;
#pragma unroll
      for (int r = 0; r < 4; ++r) {
        const float v = acc[i][j][r];
        CT* p = &Cb[(long)(row_base + r) * ldc + col];
        if constexpr (std::is_same<CT, float>::value)
          *p = v;
        else
          *p = __float2bfloat16(v);
      }
    }
  }
}

// ---------------- host launch ----------------------------------------------
extern "C" void kernel_launch(void* const* d_in, const int* in_sizes, int n_in,
                              void* d_out, int out_size, void* d_ws, size_t ws_size,
                              hipStream_t stream) {
  const float* X = (const float*)d_in[0];
  float* out = (float*)d_out;
  // Scratch: Xt lives in d_out (33.5MB of 67MB); gram (bf16, 4.19MB) in ws.
  __hip_bfloat16* Xt = (__hip_bfloat16*)d_out;
  __hip_bfloat16* gram = (__hip_bfloat16*)d_ws;

  // k1: Xt[b][d][s] = bf16(X[b][s][d])
  transpose_cast_kernel<<<dim3(SEQ / 64, DIM / 64, BATCH), 256, 0, stream>>>(X, Xt);

  // k2: gram = Xt · Xt^T   (M=N=512, K=4096), bf16 output
  gemm_bt_kernel<false, __hip_bfloat16>
      <<<dim3(DIM / BN, DIM / BM, BATCH), 256, 0, stream>>>(
          nullptr, Xt, Xt, gram, SEQ, SEQ, SEQ, DIM,
          (long)DIM * SEQ, (long)DIM * SEQ, (long)DIM * DIM);

  // k3: out = X · gram^T  (gram symmetric), M=4096, N=512, K=512, fp32 output
  gemm_bt_kernel<true, float>
      <<<dim3(DIM / BN, SEQ / BM, BATCH), 256, 0, stream>>>(
          X, nullptr, gram, out, DIM, DIM, DIM, DIM,
          (long)SEQ * DIM, (long)DIM * DIM, (long)SEQ * DIM);
}

// Round 2
// 197.567 us; speedup vs baseline: 1.2241x; 1.2241x over previous
//
#include <hip/hip_runtime.h>
#include <hip/hip_bf16.h>

// out[b] = X[b] @ (X[b]^T @ X[b]);  B=8, S=4096, D=512, fp32 in/out.
// Pipeline (all bf16 MFMA, fp32 accumulate):
//   k1: Xt = bf16 transpose of X          -> d_out[0 : 33.5MB)
//   k2: split-K gram partials (fp32)      -> d_out[33.5MB : 67MB)  [b][split][D][D]
//   kr: reduce 4 partials -> bf16 gram    -> ws (4.2MB)
//   k3: out(fp32) = X . gram^T            -> d_out (overwrites scratch; safe by stream order)

typedef __attribute__((ext_vector_type(8))) short short8;
typedef __attribute__((ext_vector_type(4))) float floatx4;

#define BM 128
#define BN 128
#define BK 32

#define BATCH 8
#define SEQ 4096
#define DIM 512
#define NSPLIT_K2 4

__device__ __forceinline__ void async_copy16(const __hip_bfloat16* g, __hip_bfloat16* l) {
  __builtin_amdgcn_global_load_lds((const __attribute__((address_space(1))) void*)g,
                                   (__attribute__((address_space(3))) void*)l, 16, 0, 0);
}

// ---------------- k1: transpose + cast, vectorized 16B stores ---------------
__global__ __launch_bounds__(256) void transpose_cast_kernel(
    const float* __restrict__ X, __hip_bfloat16* __restrict__ Xt) {
  __shared__ float tile[64][65];
  const int b = blockIdx.z;
  const int s0 = blockIdx.x * 64;
  const int d0 = blockIdx.y * 64;
  const int tid = threadIdx.x;
  const int tx = tid & 63;
  const int ty = tid >> 6;  // 0..3
  const float* Xb = X + (long)b * SEQ * DIM;
  __hip_bfloat16* Xtb = Xt + (long)b * DIM * SEQ;
  // load: tile[s_local][d_local], coalesced global reads, conflict-free LDS writes
#pragma unroll
  for (int r = 0; r < 64; r += 4)
    tile[r + ty][tx] = Xb[(long)(s0 + r + ty) * DIM + d0 + tx];
  __syncthreads();
  // store: each thread packs 8 consecutive s for one d-row -> one 16B store.
  // LDS read addr = (so+j)*65 + dl; mod 32 = (so + j + dl) -> 2 lanes/bank (free).
#pragma unroll
  for (int it = 0; it < 2; ++it) {
    const int idx = it * 256 + tid;    // 0..511
    const int dl = idx >> 3;           // 0..63
    const int so = (idx & 7) * 8;      // 0,8,..,56
    union { short8 v; __hip_bfloat16 e[8]; } u;
#pragma unroll
    for (int j = 0; j < 8; ++j) u.e[j] = __float2bfloat16(tile[so + j][dl]);
    *(short8*)&Xtb[(long)(d0 + dl) * SEQ + s0 + so] = u.v;
  }
}

// ---------------- GEMM: C = A . Bt^T (Bt stored [N][K], K-contiguous) -------
// NSPLIT: split-K factor; blockIdx.z = b*NSPLIT + split, C indexed by [b][split].
// AFP32=false: A bf16 [M][K] staged via global_load_lds (16B).
// AFP32=true : A fp32 [M][K] staged via float4 loads + cast + ds_write_b128.
template <int NSPLIT, bool AFP32>
__global__ __launch_bounds__(256) void gemm_bt_kernel(
    const float* __restrict__ Af, const __hip_bfloat16* __restrict__ Ab,
    const __hip_bfloat16* __restrict__ Bt, float* __restrict__ C,
    int K, int lda, int ldb, int ldc, long strideA, long strideB, long strideC) {
  __shared__ __align__(16) __hip_bfloat16 As[BM * BK];  // [m][k], 64B rows
  __shared__ __align__(16) __hip_bfloat16 Bs[BN * BK];  // [n][k]

  const int bz = blockIdx.z;
  const int b = bz / NSPLIT;
  const int split = bz % NSPLIT;
  const int klen = K / NSPLIT;
  const int kb = split * klen;

  const int m0 = blockIdx.y * BM;
  const int n0 = blockIdx.x * BN;
  const int tid = threadIdx.x;
  const int w = tid >> 6;        // wave 0..3
  const int lane = tid & 63;
  const int r16 = lane & 15;
  const int kg = lane >> 4;      // 0..3
  const int wr = w >> 1;
  const int wc = w & 1;

  const float* Afb = AFP32 ? Af + b * strideA : nullptr;
  const __hip_bfloat16* Abb = AFP32 ? nullptr : Ab + b * strideA;
  const __hip_bfloat16* Btb = Bt + b * strideB;
  float* Cb = C + (long)bz * strideC;

  const floatx4 vzero = {0.f, 0.f, 0.f, 0.f};
  floatx4 acc[4][4];
#pragma unroll
  for (int i = 0; i < 4; ++i)
#pragma unroll
    for (int j = 0; j < 4; ++j) acc[i][j] = vzero;

  for (int k0 = kb; k0 < kb + klen; k0 += BK) {
    // ---- stage B (bf16, async direct-to-LDS, 16B/lane) ----
#pragma unroll
    for (int q = 0; q < 2; ++q) {
      const __hip_bfloat16* gb =
          Btb + (long)(n0 + w * 32 + q * 16 + (lane >> 2)) * ldb + k0 + (lane & 3) * 8;
      async_copy16(gb, &Bs[(w * 32 + q * 16) * BK]);
    }
    // ---- stage A ----
    if constexpr (!AFP32) {
#pragma unroll
      for (int q = 0; q < 2; ++q) {
        const __hip_bfloat16* ga =
            Abb + (long)(m0 + w * 32 + q * 16 + (lane >> 2)) * lda + k0 + (lane & 3) * 8;
        async_copy16(ga, &As[(w * 32 + q * 16) * BK]);
      }
    } else {
      const int row = tid >> 1;           // 0..127
      const int half = tid & 1;
      const float* ar = Afb + (long)(m0 + row) * lda + k0 + half * 16;
      float f[16];
      *(float4*)(f + 0)  = *(const float4*)(ar + 0);
      *(float4*)(f + 4)  = *(const float4*)(ar + 4);
      *(float4*)(f + 8)  = *(const float4*)(ar + 8);
      *(float4*)(f + 12) = *(const float4*)(ar + 12);
      union { short8 v[2]; __hip_bfloat16 e[16]; } u;
#pragma unroll
      for (int t = 0; t < 16; ++t) u.e[t] = __float2bfloat16(f[t]);
      short8* dst = (short8*)&As[row * BK + half * 16];
      dst[0] = u.v[0];
      dst[1] = u.v[1];
    }
    __syncthreads();

    short8 a[4], bfrag[4];
#pragma unroll
    for (int i = 0; i < 4; ++i)
      a[i] = *(const short8*)&As[(wr * 64 + i * 16 + r16) * BK + kg * 8];
#pragma unroll
    for (int j = 0; j < 4; ++j)
      bfrag[j] = *(const short8*)&Bs[(wc * 64 + j * 16 + r16) * BK + kg * 8];
#pragma unroll
    for (int i = 0; i < 4; ++i)
#pragma unroll
      for (int j = 0; j < 4; ++j)
        acc[i][j] = __builtin_amdgcn_mfma_f32_16x16x32_bf16(a[i], bfrag[j], acc[i][j], 0, 0, 0);
    __syncthreads();
  }

  // epilogue: row = kg*4 + r, col = r16 (m89-verified C/D map)
#pragma unroll
  for (int i = 0; i < 4; ++i) {
    const int row_base = m0 + wr * 64 + i * 16 + kg * 4;
#pragma unroll
    for (int j = 0; j < 4; ++j) {
      const int col = n0 + wc * 64 + j * 16 + r16;
#pragma unroll
      for (int r = 0; r < 4; ++r)
        Cb[(long)(row_base + r) * ldc + col] = acc[i][j][r];
    }
  }
}

// ---------------- kr: reduce 4 fp32 partials -> bf16 gram -------------------
__global__ __launch_bounds__(256) void reduce_cast_kernel(
    const float* __restrict__ P, __hip_bfloat16* __restrict__ G) {
  const int DD4 = DIM * DIM / 4;  // 65536 float4 per [b][split]
  const long idx = (long)blockIdx.x * 256 + threadIdx.x;  // 0 .. B*DD4
  const int b = (int)(idx / DD4);
  const int e = (int)(idx % DD4);
  const float4* base = (const float4*)P + (long)(b * NSPLIT_K2) * DD4 + e;
  float4 s0 = base[0];
  float4 s1 = base[DD4];
  float4 s2 = base[2 * DD4];
  float4 s3 = base[3 * DD4];
  float4 s;
  s.x = (s0.x + s1.x) + (s2.x + s3.x);
  s.y = (s0.y + s1.y) + (s2.y + s3.y);
  s.z = (s0.z + s1.z) + (s2.z + s3.z);
  s.w = (s0.w + s1.w) + (s2.w + s3.w);
  union { short s4[4]; uint2 v; } u;
  u.s4[0] = __bfloat16_as_short(__float2bfloat16(s.x));
  u.s4[1] = __bfloat16_as_short(__float2bfloat16(s.y));
  u.s4[2] = __bfloat16_as_short(__float2bfloat16(s.z));
  u.s4[3] = __bfloat16_as_short(__float2bfloat16(s.w));
  *(uint2*)&G[idx * 4] = u.v;
}

// ---------------- host launch ----------------------------------------------
extern "C" void kernel_launch(void* const* d_in, const int* in_sizes, int n_in,
                              void* d_out, int out_size, void* d_ws, size_t ws_size,
                              hipStream_t stream) {
  const float* X = (const float*)d_in[0];
  float* out = (float*)d_out;
  // d_out scratch layout: [0, 33.5MB) Xt bf16 ; [33.5MB, 67MB) fp32 gram partials
  __hip_bfloat16* Xt = (__hip_bfloat16*)d_out;
  float* partials = (float*)((char*)d_out + (long)BATCH * DIM * SEQ * 2);
  __hip_bfloat16* gram = (__hip_bfloat16*)d_ws;

  // k1: Xt[b][d][s] = bf16(X[b][s][d])
  transpose_cast_kernel<<<dim3(SEQ / 64, DIM / 64, BATCH), 256, 0, stream>>>(X, Xt);

  // k2: gram partials = Xt-chunk . Xt-chunk^T  (M=N=512, K=4096, split 4)
  gemm_bt_kernel<NSPLIT_K2, false>
      <<<dim3(DIM / BN, DIM / BM, BATCH * NSPLIT_K2), 256, 0, stream>>>(
          nullptr, Xt, Xt, partials, SEQ, SEQ, SEQ, DIM,
          (long)DIM * SEQ, (long)DIM * SEQ, (long)DIM * DIM);

  // kr: gram(bf16, ws) = sum over 4 partials
  reduce_cast_kernel<<<dim3(BATCH * DIM * DIM / 4 / 256), 256, 0, stream>>>(
      partials, gram);

  // k3: out = X . gram^T  (gram symmetric), M=4096, N=512, K=512
  gemm_bt_kernel<1, true>
      <<<dim3(DIM / BN, SEQ / BM, BATCH), 256, 0, stream>>>(
          X, nullptr, gram, out, DIM, DIM, DIM, DIM,
          (long)SEQ * DIM, (long)DIM * DIM, (long)SEQ * DIM);
}

// Round 3
// 187.105 us; speedup vs baseline: 1.2926x; 1.0559x over previous
//
#include <hip/hip_runtime.h>
#include <hip/hip_bf16.h>

// out[b] = X[b] @ (X[b]^T @ X[b]);  B=8, S=4096, D=512, fp32 in/out.
// Pipeline (bf16 MFMA, fp32 accumulate):
//   k1: Xt[d][s] = bf16 transpose (d_out[0:33.5M)) ; Xb16[s][d] = bf16 cast (ws+4.2M, if ws fits)
//   k2: split-K=4 gram partials fp32 -> d_out[33.5M:67M)
//   kr: reduce partials -> bf16 gram -> ws[0:4.2M)
//   k3: out = Xb16 . gram^T (both K-contiguous, async-LDS) -> d_out
//       fallback (small ws): A = fp32 X from d_in with cast-in-staging + reg prefetch.

typedef __attribute__((ext_vector_type(8))) short short8;
typedef __attribute__((ext_vector_type(4))) float floatx4;

#define BM 128
#define BN 128
#define BK 32

#define BATCH 8
#define SEQ 4096
#define DIM 512
#define NSPLIT_K2 4

__device__ __forceinline__ void async_copy16(const __hip_bfloat16* g, __hip_bfloat16* l) {
  __builtin_amdgcn_global_load_lds((const __attribute__((address_space(1))) void*)g,
                                   (__attribute__((address_space(3))) void*)l, 16, 0, 0);
}

// ---------------- k1: transpose+cast (Xt) and optional straight cast (Xb16) --
__global__ __launch_bounds__(256) void transpose_cast_kernel(
    const float* __restrict__ X, __hip_bfloat16* __restrict__ Xt,
    __hip_bfloat16* __restrict__ Xb16) {
  __shared__ float tile[64][65];
  const int b = blockIdx.z;
  const int s0 = blockIdx.x * 64;
  const int d0 = blockIdx.y * 64;
  const int tid = threadIdx.x;
  const int tx = tid & 63;
  const int ty = tid >> 6;  // 0..3
  const float* Xb = X + (long)b * SEQ * DIM;
  __hip_bfloat16* Xtb = Xt + (long)b * DIM * SEQ;
#pragma unroll
  for (int r = 0; r < 64; r += 4)
    tile[r + ty][tx] = Xb[(long)(s0 + r + ty) * DIM + d0 + tx];
  __syncthreads();
  // Xt[d][s]: pack 8 consecutive s per 16B store.
#pragma unroll
  for (int it = 0; it < 2; ++it) {
    const int idx = it * 256 + tid;    // 0..511
    const int dl = idx >> 3;           // 0..63
    const int so = (idx & 7) * 8;      // 0,8,..,56
    union { short8 v; __hip_bfloat16 e[8]; } u;
#pragma unroll
    for (int j = 0; j < 8; ++j) u.e[j] = __float2bfloat16(tile[so + j][dl]);
    *(short8*)&Xtb[(long)(d0 + dl) * SEQ + s0 + so] = u.v;
  }
  // Xb16[s][d]: straight cast, pack 8 consecutive d per 16B store.
  if (Xb16 != nullptr) {
    __hip_bfloat16* Xcb = Xb16 + (long)b * SEQ * DIM;
#pragma unroll
    for (int it = 0; it < 2; ++it) {
      const int idx = it * 256 + tid;  // 0..511
      const int sl = idx >> 3;         // 0..63
      const int dc = idx & 7;          // 8-wide d chunk
      union { short8 v; __hip_bfloat16 e[8]; } u;
#pragma unroll
      for (int j = 0; j < 8; ++j) u.e[j] = __float2bfloat16(tile[sl][dc * 8 + j]);
      *(short8*)&Xcb[(long)(s0 + sl) * DIM + d0 + dc * 8] = u.v;
    }
  }
}

// ---------------- GEMM: C = A . Bt^T (Bt stored [N][K], K-contiguous) -------
// NSPLIT: split-K factor (blockIdx.z = b*NSPLIT+split).
// AFP32: A fp32 cast-in-staging (w/ next-iter register prefetch); else bf16 async.
// SWZ: XCD-aware remap, grid = dim3(128,1,B): 4 n-blocks per A-slab on one XCD.
template <int NSPLIT, bool AFP32, bool SWZ>
__global__ __launch_bounds__(256) void gemm_bt_kernel(
    const float* __restrict__ Af, const __hip_bfloat16* __restrict__ Ab,
    const __hip_bfloat16* __restrict__ Bt, float* __restrict__ C,
    int K, int lda, int ldb, int ldc, long strideA, long strideB, long strideC) {
  __shared__ __align__(16) __hip_bfloat16 As[BM * BK];  // [m][k], 64B rows
  __shared__ __align__(16) __hip_bfloat16 Bs[BN * BK];  // [n][k]

  int bz, m0, n0;
  if constexpr (SWZ) {
    const int lin = blockIdx.x;        // 0..127 per batch
    bz = blockIdx.z;
    const int xcd = lin & 7;
    const int t = lin >> 3;            // 0..15
    n0 = (t & 3) * BN;
    m0 = ((t >> 2) * 8 + xcd) * BM;    // m % 8 == xcd -> slab stays on one XCD L2
  } else {
    bz = blockIdx.z;
    m0 = blockIdx.y * BM;
    n0 = blockIdx.x * BN;
  }
  const int b = bz / NSPLIT;
  const int split = bz % NSPLIT;
  const int klen = K / NSPLIT;
  const int kb = split * klen;

  const int tid = threadIdx.x;
  const int w = tid >> 6;
  const int lane = tid & 63;
  const int r16 = lane & 15;
  const int kg = lane >> 4;
  const int wr = w >> 1;
  const int wc = w & 1;

  const float* Afb = AFP32 ? Af + b * strideA : nullptr;
  const __hip_bfloat16* Abb = AFP32 ? nullptr : Ab + b * strideA;
  const __hip_bfloat16* Btb = Bt + b * strideB;
  float* Cb = C + (long)bz * strideC;

  const floatx4 vzero = {0.f, 0.f, 0.f, 0.f};
  floatx4 acc[4][4];
#pragma unroll
  for (int i = 0; i < 4; ++i)
#pragma unroll
    for (int j = 0; j < 4; ++j) acc[i][j] = vzero;

  // fp32-A staging registers (prefetched one iteration ahead)
  const int arow = tid >> 1;
  const int ahalf = tid & 1;
  float f[16];
  if constexpr (AFP32) {
    const float* ar = Afb + (long)(m0 + arow) * lda + kb + ahalf * 16;
    *(float4*)(f + 0)  = *(const float4*)(ar + 0);
    *(float4*)(f + 4)  = *(const float4*)(ar + 4);
    *(float4*)(f + 8)  = *(const float4*)(ar + 8);
    *(float4*)(f + 12) = *(const float4*)(ar + 12);
  }

  for (int k0 = kb; k0 < kb + klen; k0 += BK) {
    // ---- stage B (bf16 async direct-to-LDS, 16B/lane) ----
#pragma unroll
    for (int q = 0; q < 2; ++q) {
      const __hip_bfloat16* gb =
          Btb + (long)(n0 + w * 32 + q * 16 + (lane >> 2)) * ldb + k0 + (lane & 3) * 8;
      async_copy16(gb, &Bs[(w * 32 + q * 16) * BK]);
    }
    // ---- stage A ----
    if constexpr (!AFP32) {
#pragma unroll
      for (int q = 0; q < 2; ++q) {
        const __hip_bfloat16* ga =
            Abb + (long)(m0 + w * 32 + q * 16 + (lane >> 2)) * lda + k0 + (lane & 3) * 8;
        async_copy16(ga, &As[(w * 32 + q * 16) * BK]);
      }
    } else {
      union { short8 v[2]; __hip_bfloat16 e[16]; } u;
#pragma unroll
      for (int t = 0; t < 16; ++t) u.e[t] = __float2bfloat16(f[t]);
      short8* dst = (short8*)&As[arow * BK + ahalf * 16];
      dst[0] = u.v[0];
      dst[1] = u.v[1];
    }
    __syncthreads();

    // prefetch next iteration's fp32 A while MFMAs run
    if constexpr (AFP32) {
      if (k0 + BK < kb + klen) {
        const float* ar = Afb + (long)(m0 + arow) * lda + (k0 + BK) + ahalf * 16;
        *(float4*)(f + 0)  = *(const float4*)(ar + 0);
        *(float4*)(f + 4)  = *(const float4*)(ar + 4);
        *(float4*)(f + 8)  = *(const float4*)(ar + 8);
        *(float4*)(f + 12) = *(const float4*)(ar + 12);
      }
    }

    short8 a[4], bfrag[4];
#pragma unroll
    for (int i = 0; i < 4; ++i)
      a[i] = *(const short8*)&As[(wr * 64 + i * 16 + r16) * BK + kg * 8];
#pragma unroll
    for (int j = 0; j < 4; ++j)
      bfrag[j] = *(const short8*)&Bs[(wc * 64 + j * 16 + r16) * BK + kg * 8];
#pragma unroll
    for (int i = 0; i < 4; ++i)
#pragma unroll
      for (int j = 0; j < 4; ++j)
        acc[i][j] = __builtin_amdgcn_mfma_f32_16x16x32_bf16(a[i], bfrag[j], acc[i][j], 0, 0, 0);
    __syncthreads();
  }

  // epilogue: row = kg*4 + r, col = r16 (m89-verified C/D map)
#pragma unroll
  for (int i = 0; i < 4; ++i) {
    const int row_base = m0 + wr * 64 + i * 16 + kg * 4;
#pragma unroll
    for (int j = 0; j < 4; ++j) {
      const int col = n0 + wc * 64 + j * 16 + r16;
#pragma unroll
      for (int r = 0; r < 4; ++r)
        Cb[(long)(row_base + r) * ldc + col] = acc[i][j][r];
    }
  }
}

// ---------------- kr: reduce 4 fp32 partials -> bf16 gram -------------------
__global__ __launch_bounds__(256) void reduce_cast_kernel(
    const float* __restrict__ P, __hip_bfloat16* __restrict__ G) {
  const int DD4 = DIM * DIM / 4;
  const long idx = (long)blockIdx.x * 256 + threadIdx.x;
  const int b = (int)(idx / DD4);
  const int e = (int)(idx % DD4);
  const float4* base = (const float4*)P + (long)(b * NSPLIT_K2) * DD4 + e;
  float4 s0 = base[0];
  float4 s1 = base[DD4];
  float4 s2 = base[2 * DD4];
  float4 s3 = base[3 * DD4];
  float4 s;
  s.x = (s0.x + s1.x) + (s2.x + s3.x);
  s.y = (s0.y + s1.y) + (s2.y + s3.y);
  s.z = (s0.z + s1.z) + (s2.z + s3.z);
  s.w = (s0.w + s1.w) + (s2.w + s3.w);
  union { short s4[4]; uint2 v; } u;
  u.s4[0] = __bfloat16_as_short(__float2bfloat16(s.x));
  u.s4[1] = __bfloat16_as_short(__float2bfloat16(s.y));
  u.s4[2] = __bfloat16_as_short(__float2bfloat16(s.z));
  u.s4[3] = __bfloat16_as_short(__float2bfloat16(s.w));
  *(uint2*)&G[idx * 4] = u.v;
}

// ---------------- host launch ----------------------------------------------
extern "C" void kernel_launch(void* const* d_in, const int* in_sizes, int n_in,
                              void* d_out, int out_size, void* d_ws, size_t ws_size,
                              hipStream_t stream) {
  const float* X = (const float*)d_in[0];
  float* out = (float*)d_out;
  const long xtBytes = (long)BATCH * DIM * SEQ * 2;        // 33.5 MB
  const long gramBytes = (long)BATCH * DIM * DIM * 2;      // 4.2 MB
  __hip_bfloat16* Xt = (__hip_bfloat16*)d_out;
  float* partials = (float*)((char*)d_out + xtBytes);
  __hip_bfloat16* gram = (__hip_bfloat16*)d_ws;
  const bool fast = ws_size >= (size_t)(gramBytes + xtBytes);
  __hip_bfloat16* Xb16 = fast ? (__hip_bfloat16*)((char*)d_ws + gramBytes) : nullptr;

  // k1: Xt[b][d][s] (+ Xb16[b][s][d] if ws fits)
  transpose_cast_kernel<<<dim3(SEQ / 64, DIM / 64, BATCH), 256, 0, stream>>>(X, Xt, Xb16);

  // k2: gram partials = Xt-chunk . Xt-chunk^T  (M=N=512, K=4096, split 4)
  gemm_bt_kernel<NSPLIT_K2, false, false>
      <<<dim3(DIM / BN, DIM / BM, BATCH * NSPLIT_K2), 256, 0, stream>>>(
          nullptr, Xt, Xt, partials, SEQ, SEQ, SEQ, DIM,
          (long)DIM * SEQ, (long)DIM * SEQ, (long)DIM * DIM);

  // kr: gram(bf16, ws) = sum of partials
  reduce_cast_kernel<<<dim3(BATCH * DIM * DIM / 4 / 256), 256, 0, stream>>>(
      partials, gram);

  // k3: out = A . gram^T (M=4096, N=512, K=512), XCD-swizzled
  if (fast) {
    gemm_bt_kernel<1, false, true><<<dim3(128, 1, BATCH), 256, 0, stream>>>(
        nullptr, Xb16, gram, out, DIM, DIM, DIM, DIM,
        (long)SEQ * DIM, (long)DIM * DIM, (long)SEQ * DIM);
  } else {
    gemm_bt_kernel<1, true, true><<<dim3(128, 1, BATCH), 256, 0, stream>>>(
        X, nullptr, gram, out, DIM, DIM, DIM, DIM,
        (long)SEQ * DIM, (long)DIM * DIM, (long)SEQ * DIM);
  }
}